// Round 3
// baseline (5331.654 us; speedup 1.0000x reference)
//
#include <hip/hip_runtime.h>
#include <stdint.h>

typedef _Float16 half8 __attribute__((ext_vector_type(8)));
typedef float f32x4 __attribute__((ext_vector_type(4)));

static constexpr int BN_ = 64;    // batch
static constexpr int TT_ = 512;   // time steps
static constexpr int II_ = 256;   // input dim
static constexpr int HH_ = 512;   // hidden dim
static constexpr int GG_ = 2048;  // 4*H
static constexpr int OO_ = 256;   // output dim

// workspace layout (bytes)
static constexpr size_t GX_OFF     = 0;
static constexpr size_t GX_BYTES   = (size_t)TT_ * BN_ * GG_ * 2;   // 128 MiB, fp16 [t][b][g']
static constexpr size_t HALL_OFF   = GX_OFF + GX_BYTES;
static constexpr size_t HALL_BYTES = (size_t)BN_ * TT_ * HH_ * 2;   // 32 MiB, fp16 [b][t][u]
static constexpr size_t HX2_OFF    = HALL_OFF + HALL_BYTES;
static constexpr size_t HX2_BYTES  = (size_t)2 * BN_ * HH_ * 4;     // tagged h words, 2 slots
static constexpr size_t WS_NEEDED  = HX2_OFF + HX2_BYTES;

__device__ __forceinline__ float sigm(float x)  { return 1.0f / (1.0f + __expf(-x)); }
__device__ __forceinline__ float tanha(float x) { return 1.0f - 2.0f / (__expf(2.0f * x) + 1.0f); }

__device__ __forceinline__ half8 cvt8(float4 a, float4 b) {
  half8 r;
  r[0]=(_Float16)a.x; r[1]=(_Float16)a.y; r[2]=(_Float16)a.z; r[3]=(_Float16)a.w;
  r[4]=(_Float16)b.x; r[5]=(_Float16)b.y; r[6]=(_Float16)b.z; r[7]=(_Float16)b.w;
  return r;
}

// ---------------------------------------------------------------------------
// Kernel 1: gates_x[t][b][g'] = (x @ W_ih.T)[b,t,R(g')] + b_ih[R] + b_hh[R]
// g' = 4*u + gate; R(g') = (g'&3)*512 + (g'>>2)
// ---------------------------------------------------------------------------
__global__ __launch_bounds__(256) void gates_gemm_k(
    const float* __restrict__ x, const float* __restrict__ Wih,
    const float* __restrict__ bih, const float* __restrict__ bhh,
    _Float16* __restrict__ gx)
{
  __shared__ _Float16 As[128][40];
  __shared__ _Float16 Bs[128][40];
  const int bn = blockIdx.x & 15;
  const int bm = blockIdx.x >> 4;
  const int M0 = bm * 128, N0 = bn * 128;
  const int tid = threadIdx.x;
  const int w = tid >> 6, l = tid & 63, lg = l >> 4, ln = l & 15;
  const int wm = w & 1, wn = w >> 1;
  const int sr = tid >> 1, sp = tid & 1;
  const int nglob = N0 + sr;
  const int Rrow = (nglob & 3) * HH_ + (nglob >> 2);

  f32x4 acc[4][4];
  #pragma unroll
  for (int i = 0; i < 4; i++) {
    #pragma unroll
    for (int j = 0; j < 4; j++) acc[i][j] = (f32x4){0.f, 0.f, 0.f, 0.f};
  }

  for (int K0 = 0; K0 < II_; K0 += 32) {
    __syncthreads();
    {
      const float* s0 = x + (size_t)(M0 + sr) * II_ + K0 + sp * 16;
      float4 f0 = ((const float4*)s0)[0], f1 = ((const float4*)s0)[1];
      float4 f2 = ((const float4*)s0)[2], f3 = ((const float4*)s0)[3];
      *(half8*)&As[sr][sp * 16]     = cvt8(f0, f1);
      *(half8*)&As[sr][sp * 16 + 8] = cvt8(f2, f3);
      const float* s1 = Wih + (size_t)Rrow * II_ + K0 + sp * 16;
      float4 g0 = ((const float4*)s1)[0], g1 = ((const float4*)s1)[1];
      float4 g2 = ((const float4*)s1)[2], g3 = ((const float4*)s1)[3];
      *(half8*)&Bs[sr][sp * 16]     = cvt8(g0, g1);
      *(half8*)&Bs[sr][sp * 16 + 8] = cvt8(g2, g3);
    }
    __syncthreads();
    half8 af[4], bf[4];
    #pragma unroll
    for (int i = 0; i < 4; i++) af[i] = *(const half8*)&As[wm * 64 + i * 16 + ln][lg * 8];
    #pragma unroll
    for (int j = 0; j < 4; j++) bf[j] = *(const half8*)&Bs[wn * 64 + j * 16 + ln][lg * 8];
    #pragma unroll
    for (int i = 0; i < 4; i++) {
      #pragma unroll
      for (int j = 0; j < 4; j++)
        acc[i][j] = __builtin_amdgcn_mfma_f32_16x16x32_f16(af[i], bf[j], acc[i][j], 0, 0, 0);
    }
  }

  #pragma unroll
  for (int j = 0; j < 4; j++) {
    const int ncol = N0 + wn * 64 + j * 16 + ln;
    const int R = (ncol & 3) * HH_ + (ncol >> 2);
    const float bias = bih[R] + bhh[R];
    #pragma unroll
    for (int i = 0; i < 4; i++) {
      #pragma unroll
      for (int rr = 0; rr < 4; rr++) {
        const int m = M0 + wm * 64 + i * 16 + lg * 4 + rr;
        const int bb = m >> 9, tt = m & 511;
        gx[(size_t)tt * (BN_ * GG_) + (size_t)bb * GG_ + ncol] =
            (_Float16)(acc[i][j][rr] + bias);
      }
    }
  }
}

// ---------------------------------------------------------------------------
// Kernel 2: persistent LSTM recurrence — tagged-word dataflow.
// 64 blocks = 4 batch-groups x 16 unit-slices. W_hh resident in regs.
// Published h word = (step<<16) | fp16bits(h). Producer fire-and-forget;
// consumer polls the payload words themselves (no flags, no drains, no
// __syncthreads in the loop). 2-slot parity buffer; tag monotonicity makes
// WAW safe at wave granularity.
// ---------------------------------------------------------------------------
__global__ __launch_bounds__(256, 1) void lstm_rec_k(
    const float* __restrict__ Whh, const _Float16* __restrict__ gx,
    _Float16* __restrict__ hall, uint32_t* __restrict__ hx2)
{
  const int bid = blockIdx.x;
  const int mg = bid >> 4, nb = bid & 15;
  const int tid = threadIdx.x;
  const int w = tid >> 6, l = tid & 63, lg = l >> 4, ln = l & 15;
  const int batch = mg * 16 + ln;

  // Preload W_hh fragments: A[row=gate-row g'][k=unit], rows permuted g'=4u+gate.
  half8 a0[16], a1[16];
  #pragma unroll
  for (int s2 = 0; s2 < 2; s2++) {
    const int gp = nb * 128 + (2 * w + s2) * 16 + ln;
    const int Rr = (gp & 3) * HH_ + (gp >> 2);
    const float* wp = Whh + (size_t)Rr * HH_;
    #pragma unroll
    for (int ks = 0; ks < 16; ks++) {
      const float* p = wp + ks * 32 + lg * 8;
      float4 f0 = ((const float4*)p)[0];
      float4 f1 = ((const float4*)p)[1];
      if (s2 == 0) a0[ks] = cvt8(f0, f1); else a1[ks] = cvt8(f0, f1);
    }
  }

  const int u0 = nb * 32 + 8 * w + lg;       // hidden unit of acc0's lane
  const int u1 = u0 + 4;                     // hidden unit of acc1's lane
  const int g0 = nb * 128 + 32 * w + lg * 4; // first gate-row (i-gate) of u0

  float c0 = 0.f, c1 = 0.f;

  for (int s = 1; s <= TT_; ++s) {
    const int t = s - 1;
    // gx prefetch (in flight while we poll)
    const _Float16* gxp = gx + (size_t)t * (BN_ * GG_) + (size_t)batch * GG_ + g0;
    uint2 ga = *(const uint2*)gxp;
    uint2 gb = *(const uint2*)(gxp + 16);

    const uint32_t stag = (uint32_t)t << 16;
    const unsigned long long* hin = (const unsigned long long*)(
        hx2 + (size_t)(t & 1) * (BN_ * HH_) + (size_t)batch * HH_);

    f32x4 acc0 = {0.f, 0.f, 0.f, 0.f}, acc1 = {0.f, 0.f, 0.f, 0.f};
    #pragma unroll
    for (int cc = 0; cc < 4; cc++) {     // 4 chunks of 4 k-slices
      unsigned long long q[16];
      int guard = 0;
      while (true) {
        #pragma unroll
        for (int j = 0; j < 16; j++) {
          const int ks = cc * 4 + (j >> 2);
          const int qi = lg * 4 + ks * 16 + (j & 3);   // b64 index in this row
          q[j] = __hip_atomic_load(hin + qi, __ATOMIC_RELAXED, __HIP_MEMORY_SCOPE_SYSTEM);
        }
        uint32_t bad = 0;
        #pragma unroll
        for (int j = 0; j < 16; j++) {
          bad |= ((uint32_t)q[j] ^ stag);
          bad |= ((uint32_t)(q[j] >> 32) ^ stag);
        }
        if ((bad & 0xFFFF0000u) == 0) break;
        if (++guard > (1 << 20)) break;  // safety valve: wrong-but-visible, no hang
      }
      #pragma unroll
      for (int jk = 0; jk < 4; jk++) {
        half8 bfr;
        uint32_t* bw = (uint32_t*)&bfr;
        #pragma unroll
        for (int p = 0; p < 4; p++) {
          unsigned long long qq = q[jk * 4 + p];
          // pack the two fp16 payloads (lo16 of each word) into one b32
          bw[p] = __builtin_amdgcn_perm((uint32_t)(qq >> 32), (uint32_t)qq, 0x05040100u);
        }
        acc0 = __builtin_amdgcn_mfma_f32_16x16x32_f16(a0[cc * 4 + jk], bfr, acc0, 0, 0, 0);
        acc1 = __builtin_amdgcn_mfma_f32_16x16x32_f16(a1[cc * 4 + jk], bfr, acc1, 0, 0, 0);
      }
    }

    // lane-local cell update: acc regs = i,f,g,o preacts (recurrent part)
    union { uint2 u; _Float16 h[4]; } ua, ub;
    ua.u = ga; ub.u = gb;
    float iv = sigm(acc0[0] + (float)ua.h[0]);
    float fv = sigm(acc0[1] + (float)ua.h[1]);
    float gv = tanha(acc0[2] + (float)ua.h[2]);
    float ov = sigm(acc0[3] + (float)ua.h[3]);
    c0 = fv * c0 + iv * gv;
    const float h0 = ov * tanha(c0);

    iv = sigm(acc1[0] + (float)ub.h[0]);
    fv = sigm(acc1[1] + (float)ub.h[1]);
    gv = tanha(acc1[2] + (float)ub.h[2]);
    ov = sigm(acc1[3] + (float)ub.h[3]);
    c1 = fv * c1 + iv * gv;
    const float h1 = ov * tanha(c1);

    // publish tagged h first (the latency-critical stores), fire-and-forget
    uint32_t* hout = hx2 + (size_t)(s & 1) * (BN_ * HH_) + (size_t)batch * HH_;
    union { _Float16 f; unsigned short us; } cv0, cv1;
    cv0.f = (_Float16)h0; cv1.f = (_Float16)h1;
    __hip_atomic_store(&hout[u0], ((uint32_t)s << 16) | (uint32_t)cv0.us,
                       __ATOMIC_RELAXED, __HIP_MEMORY_SCOPE_SYSTEM);
    __hip_atomic_store(&hout[u1], ((uint32_t)s << 16) | (uint32_t)cv1.us,
                       __ATOMIC_RELAXED, __HIP_MEMORY_SCOPE_SYSTEM);
    // hall: normal cached store (consumed by next dispatch)
    _Float16* hap = hall + (size_t)batch * (TT_ * HH_) + (size_t)t * HH_;
    hap[u0] = (_Float16)h0;
    hap[u1] = (_Float16)h1;
  }
}

// ---------------------------------------------------------------------------
// Kernel 3: out[b][t][o] = h_all[b][t][:] @ fc_W.T + fc_b   (fp32 out)
// ---------------------------------------------------------------------------
__global__ __launch_bounds__(256) void fc_gemm_k(
    const _Float16* __restrict__ hall, const float* __restrict__ fcW,
    const float* __restrict__ fcb, float* __restrict__ out)
{
  __shared__ _Float16 As[128][40];
  __shared__ _Float16 Bs[128][40];
  const int bn = blockIdx.x & 1;
  const int bm = blockIdx.x >> 1;
  const int M0 = bm * 128, N0 = bn * 128;
  const int tid = threadIdx.x;
  const int w = tid >> 6, l = tid & 63, lg = l >> 4, ln = l & 15;
  const int wm = w & 1, wn = w >> 1;
  const int sr = tid >> 1, sp = tid & 1;

  f32x4 acc[4][4];
  #pragma unroll
  for (int i = 0; i < 4; i++) {
    #pragma unroll
    for (int j = 0; j < 4; j++) acc[i][j] = (f32x4){0.f, 0.f, 0.f, 0.f};
  }

  for (int K0 = 0; K0 < HH_; K0 += 32) {
    __syncthreads();
    {
      const _Float16* s0 = hall + (size_t)(M0 + sr) * HH_ + K0 + sp * 16;
      *(uint4*)&As[sr][sp * 16]     = ((const uint4*)s0)[0];
      *(uint4*)&As[sr][sp * 16 + 8] = ((const uint4*)s0)[1];
      const float* s1 = fcW + (size_t)(N0 + sr) * HH_ + K0 + sp * 16;
      float4 g0 = ((const float4*)s1)[0], g1 = ((const float4*)s1)[1];
      float4 g2 = ((const float4*)s1)[2], g3 = ((const float4*)s1)[3];
      *(half8*)&Bs[sr][sp * 16]     = cvt8(g0, g1);
      *(half8*)&Bs[sr][sp * 16 + 8] = cvt8(g2, g3);
    }
    __syncthreads();
    half8 af[4], bf[4];
    #pragma unroll
    for (int i = 0; i < 4; i++) af[i] = *(const half8*)&As[wm * 64 + i * 16 + ln][lg * 8];
    #pragma unroll
    for (int j = 0; j < 4; j++) bf[j] = *(const half8*)&Bs[wn * 64 + j * 16 + ln][lg * 8];
    #pragma unroll
    for (int i = 0; i < 4; i++) {
      #pragma unroll
      for (int j = 0; j < 4; j++)
        acc[i][j] = __builtin_amdgcn_mfma_f32_16x16x32_f16(af[i], bf[j], acc[i][j], 0, 0, 0);
    }
  }

  #pragma unroll
  for (int j = 0; j < 4; j++) {
    const int ncol = N0 + wn * 64 + j * 16 + ln;
    const float bias = fcb[ncol];
    #pragma unroll
    for (int i = 0; i < 4; i++) {
      #pragma unroll
      for (int rr = 0; rr < 4; rr++) {
        const int m = M0 + wm * 64 + i * 16 + lg * 4 + rr;
        out[(size_t)m * OO_ + ncol] = acc[i][j][rr] + bias;
      }
    }
  }
}

extern "C" void kernel_launch(void* const* d_in, const int* in_sizes, int n_in,
                              void* d_out, int out_size, void* d_ws, size_t ws_size,
                              hipStream_t stream) {
  (void)in_sizes; (void)n_in; (void)out_size;
  if (ws_size < WS_NEEDED) return;  // diagnostic: output stays zero -> absmax ~0.39

  const float* x   = (const float*)d_in[0];
  const float* Wih = (const float*)d_in[1];
  const float* Whh = (const float*)d_in[2];
  const float* bih = (const float*)d_in[3];
  const float* bhh = (const float*)d_in[4];
  const float* fcW = (const float*)d_in[5];
  const float* fcb = (const float*)d_in[6];
  float* out = (float*)d_out;

  char* ws = (char*)d_ws;
  _Float16* gx   = (_Float16*)(ws + GX_OFF);
  _Float16* hall = (_Float16*)(ws + HALL_OFF);
  uint32_t* hx2  = (uint32_t*)(ws + HX2_OFF);

  // reset tagged h words: tag=0, h=0 == step-0 initial state (every call:
  // graph replays reuse ws)
  (void)hipMemsetAsync(ws + HX2_OFF, 0, HX2_BYTES, stream);

  gates_gemm_k<<<dim3(4096), dim3(256), 0, stream>>>(x, Wih, bih, bhh, gx);
  lstm_rec_k<<<dim3(64), dim3(256), 0, stream>>>(Whh, gx, hall, hx2);
  fc_gemm_k<<<dim3(512), dim3(256), 0, stream>>>(hall, fcW, fcb, out);
}

// Round 5
// 5078.079 us; speedup vs baseline: 1.0499x; 1.0499x over previous
//
#include <hip/hip_runtime.h>
#include <stdint.h>

typedef _Float16 half8 __attribute__((ext_vector_type(8)));
typedef float f32x4 __attribute__((ext_vector_type(4)));

static constexpr int BN_ = 64;    // batch
static constexpr int TT_ = 512;   // time steps
static constexpr int II_ = 256;   // input dim
static constexpr int HH_ = 512;   // hidden dim
static constexpr int GG_ = 2048;  // 4*H
static constexpr int OO_ = 256;   // output dim

// workspace layout (bytes)
static constexpr size_t GX_OFF     = 0;
static constexpr size_t GX_BYTES   = (size_t)TT_ * BN_ * GG_ * 2;   // 128 MiB fp16 [t][b][g']
static constexpr size_t HALL_OFF   = GX_OFF + GX_BYTES;
static constexpr size_t HALL_BYTES = (size_t)BN_ * TT_ * HH_ * 2;   // 32 MiB fp16 [b][t][u]
static constexpr size_t HX2_OFF    = HALL_OFF + HALL_BYTES;
static constexpr size_t HX2_BYTES  = (size_t)2 * BN_ * HH_ * 4;     // tagged h dwords, 2 slots
static constexpr size_t WS_NEEDED  = HX2_OFF + HX2_BYTES;

__device__ __forceinline__ float sigm(float x)  { return 1.0f / (1.0f + __expf(-x)); }
__device__ __forceinline__ float tanha(float x) { return 1.0f - 2.0f / (__expf(2.0f * x) + 1.0f); }

__device__ __forceinline__ half8 cvt8(float4 a, float4 b) {
  half8 r;
  r[0]=(_Float16)a.x; r[1]=(_Float16)a.y; r[2]=(_Float16)a.z; r[3]=(_Float16)a.w;
  r[4]=(_Float16)b.x; r[5]=(_Float16)b.y; r[6]=(_Float16)b.z; r[7]=(_Float16)b.w;
  return r;
}

// ---------------------------------------------------------------------------
// Kernel 1: gates_x[t][b][g'] = (x @ W_ih.T)[b,t,R(g')] + b_ih[R] + b_hh[R]
// g' = 4*u + gate; R(g') = (g'&3)*512 + (g'>>2)
// ---------------------------------------------------------------------------
__global__ __launch_bounds__(256) void gates_gemm_k(
    const float* __restrict__ x, const float* __restrict__ Wih,
    const float* __restrict__ bih, const float* __restrict__ bhh,
    _Float16* __restrict__ gx)
{
  __shared__ _Float16 As[128][40];
  __shared__ _Float16 Bs[128][40];
  const int bn = blockIdx.x & 15;
  const int bm = blockIdx.x >> 4;
  const int M0 = bm * 128, N0 = bn * 128;
  const int tid = threadIdx.x;
  const int w = tid >> 6, l = tid & 63, lg = l >> 4, ln = l & 15;
  const int wm = w & 1, wn = w >> 1;
  const int sr = tid >> 1, sp = tid & 1;
  const int nglob = N0 + sr;
  const int Rrow = (nglob & 3) * HH_ + (nglob >> 2);

  f32x4 acc[4][4];
  #pragma unroll
  for (int i = 0; i < 4; i++) {
    #pragma unroll
    for (int j = 0; j < 4; j++) acc[i][j] = (f32x4){0.f, 0.f, 0.f, 0.f};
  }

  for (int K0 = 0; K0 < II_; K0 += 32) {
    __syncthreads();
    {
      const float* s0 = x + (size_t)(M0 + sr) * II_ + K0 + sp * 16;
      float4 f0 = ((const float4*)s0)[0], f1 = ((const float4*)s0)[1];
      float4 f2 = ((const float4*)s0)[2], f3 = ((const float4*)s0)[3];
      *(half8*)&As[sr][sp * 16]     = cvt8(f0, f1);
      *(half8*)&As[sr][sp * 16 + 8] = cvt8(f2, f3);
      const float* s1 = Wih + (size_t)Rrow * II_ + K0 + sp * 16;
      float4 g0 = ((const float4*)s1)[0], g1 = ((const float4*)s1)[1];
      float4 g2 = ((const float4*)s1)[2], g3 = ((const float4*)s1)[3];
      *(half8*)&Bs[sr][sp * 16]     = cvt8(g0, g1);
      *(half8*)&Bs[sr][sp * 16 + 8] = cvt8(g2, g3);
    }
    __syncthreads();
    half8 af[4], bf[4];
    #pragma unroll
    for (int i = 0; i < 4; i++) af[i] = *(const half8*)&As[wm * 64 + i * 16 + ln][lg * 8];
    #pragma unroll
    for (int j = 0; j < 4; j++) bf[j] = *(const half8*)&Bs[wn * 64 + j * 16 + ln][lg * 8];
    #pragma unroll
    for (int i = 0; i < 4; i++) {
      #pragma unroll
      for (int j = 0; j < 4; j++)
        acc[i][j] = __builtin_amdgcn_mfma_f32_16x16x32_f16(af[i], bf[j], acc[i][j], 0, 0, 0);
    }
  }

  #pragma unroll
  for (int j = 0; j < 4; j++) {
    const int ncol = N0 + wn * 64 + j * 16 + ln;
    const int R = (ncol & 3) * HH_ + (ncol >> 2);
    const float bias = bih[R] + bhh[R];
    #pragma unroll
    for (int i = 0; i < 4; i++) {
      #pragma unroll
      for (int rr = 0; rr < 4; rr++) {
        const int m = M0 + wm * 64 + i * 16 + lg * 4 + rr;
        const int bb = m >> 9, tt = m & 511;
        gx[(size_t)tt * (BN_ * GG_) + (size_t)bb * GG_ + ncol] =
            (_Float16)(acc[i][j][rr] + bias);
      }
    }
  }
}

// ---------------------------------------------------------------------------
// Kernel 2: persistent LSTM recurrence — tagged dataflow + sentinel gating.
// 64 blocks = 4 batch-groups x 16 unit-slices. W_hh resident in VGPRs.
// h word = (step<<16)|fp16(h), system-scope relaxed (MALL = coherence point).
// Producer: 2 tagged stores, fire-and-forget (no drain/flag/barrier).
// Consumer: poll 1 sentinel dword/lane (lane l watches unit 8l of its own
// batch row — one word per producer wave), then ONE bulk load (tag-verified,
// selective per-chunk retry). Poll traffic 256B/wave/iter (32x less than r3).
// ---------------------------------------------------------------------------
__global__ __launch_bounds__(256, 1) void lstm_rec_k(
    const float* __restrict__ Whh, const _Float16* __restrict__ gx,
    _Float16* __restrict__ hall, uint32_t* __restrict__ hx2)
{
  const int bid = blockIdx.x;
  const int mg = bid >> 4, nb = bid & 15;
  const int tid = threadIdx.x;
  const int w = tid >> 6, l = tid & 63, lg = l >> 4, ln = l & 15;
  const int batch = mg * 16 + ln;

  // Preload W_hh fragments: A[row=gate-row g'][k=unit], rows permuted g'=4u+gate.
  half8 a0[16], a1[16];
  #pragma unroll
  for (int s2 = 0; s2 < 2; s2++) {
    const int gp = nb * 128 + 32 * w + s2 * 16 + ln;
    const int Rr = (gp & 3) * HH_ + (gp >> 2);
    const float* wp = Whh + (size_t)Rr * HH_;
    #pragma unroll
    for (int ks = 0; ks < 16; ks++) {
      const float* p = wp + ks * 32 + lg * 8;
      float4 f0 = ((const float4*)p)[0];
      float4 f1 = ((const float4*)p)[1];
      if (s2 == 0) a0[ks] = cvt8(f0, f1); else a1[ks] = cvt8(f0, f1);
    }
  }

  const int u0 = nb * 32 + 8 * w + lg;       // hidden unit of acc0's lane
  const int u1 = u0 + 4;                     // hidden unit of acc1's lane
  const int g0 = nb * 128 + 32 * w + lg * 4; // first gate-row (i-gate) of u0

  float c0 = 0.f, c1 = 0.f;

  for (int s = 1; s <= TT_; ++s) {
    const int t = s - 1;
    // gx prefetch (normal cached loads; in flight while we poll)
    const _Float16* gxp = gx + (size_t)t * (BN_ * GG_) + (size_t)batch * GG_ + g0;
    uint2 ga = *(const uint2*)gxp;
    uint2 gb = *(const uint2*)(gxp + 16);

    const uint32_t* hrow = hx2 + (size_t)(t & 1) * (BN_ * HH_) + (size_t)batch * HH_;

    // --- sentinel poll: lane l watches unit 8*l of its own batch row ---
    // (one word per producer wave; producer wave (8l>>5, (8l>>3)&3) lane
    //  ln'==batch&15 writes this word with tag t at the end of its step t)
    {
      const uint32_t* sent = hrow + 8 * l;
      uint32_t v; int guard = 0;
      do {
        v = __hip_atomic_load(sent, __ATOMIC_RELAXED, __HIP_MEMORY_SCOPE_SYSTEM);
        if (++guard > (1 << 16)) break;   // safety valve (never hit in practice)
      } while (!__all((v >> 16) == (uint32_t)t));
    }

    // --- bulk load: 4 chunks x 16 b64, tag-verified, selective retry ---
    const unsigned long long* hin = (const unsigned long long*)hrow;
    const uint32_t stag = (uint32_t)t << 16;
    f32x4 acc0 = {0.f, 0.f, 0.f, 0.f}, acc1 = {0.f, 0.f, 0.f, 0.f};
    #pragma unroll
    for (int cc = 0; cc < 4; cc++) {     // chunk = 4 k-slices
      unsigned long long q[16];
      int guard = 0;
      while (true) {
        #pragma unroll
        for (int j = 0; j < 16; j++) {
          const int ks = cc * 4 + (j >> 2);
          const int qi = lg * 4 + ks * 16 + (j & 3);   // b64 index in this row
          q[j] = __hip_atomic_load(hin + qi, __ATOMIC_RELAXED, __HIP_MEMORY_SCOPE_SYSTEM);
        }
        uint32_t bad = 0;
        #pragma unroll
        for (int j = 0; j < 16; j++) {
          bad |= ((uint32_t)q[j] ^ stag);
          bad |= ((uint32_t)(q[j] >> 32) ^ stag);
        }
        if ((bad & 0xFFFF0000u) == 0) break;   // all 32 tags fresh
        if (++guard > (1 << 16)) break;        // safety valve
      }
      #pragma unroll
      for (int jk = 0; jk < 4; jk++) {
        half8 bfr;
        uint32_t* bw = (uint32_t*)&bfr;
        #pragma unroll
        for (int p = 0; p < 4; p++) {
          unsigned long long qq = q[jk * 4 + p];
          // pack the two fp16 payloads (lo16 of each dword) into one b32
          bw[p] = __builtin_amdgcn_perm((uint32_t)(qq >> 32), (uint32_t)qq, 0x05040100u);
        }
        acc0 = __builtin_amdgcn_mfma_f32_16x16x32_f16(a0[cc * 4 + jk], bfr, acc0, 0, 0, 0);
        acc1 = __builtin_amdgcn_mfma_f32_16x16x32_f16(a1[cc * 4 + jk], bfr, acc1, 0, 0, 0);
      }
    }

    // lane-local cell update: acc regs = i,f,g,o recurrent preacts
    union { uint2 u; _Float16 h[4]; } ua, ub;
    ua.u = ga; ub.u = gb;
    float iv = sigm(acc0[0] + (float)ua.h[0]);
    float fv = sigm(acc0[1] + (float)ua.h[1]);
    float gv = tanha(acc0[2] + (float)ua.h[2]);
    float ov = sigm(acc0[3] + (float)ua.h[3]);
    c0 = fv * c0 + iv * gv;
    const float h0 = ov * tanha(c0);

    iv = sigm(acc1[0] + (float)ub.h[0]);
    fv = sigm(acc1[1] + (float)ub.h[1]);
    gv = tanha(acc1[2] + (float)ub.h[2]);
    ov = sigm(acc1[3] + (float)ub.h[3]);
    c1 = fv * c1 + iv * gv;
    const float h1 = ov * tanha(c1);

    // publish tagged h (fire-and-forget; tags carry the ordering)
    uint32_t* hout = hx2 + (size_t)(s & 1) * (BN_ * HH_) + (size_t)batch * HH_;
    union { _Float16 f; unsigned short us; } cv0, cv1;
    cv0.f = (_Float16)h0; cv1.f = (_Float16)h1;
    __hip_atomic_store(&hout[u0], ((uint32_t)s << 16) | (uint32_t)cv0.us,
                       __ATOMIC_RELAXED, __HIP_MEMORY_SCOPE_SYSTEM);
    __hip_atomic_store(&hout[u1], ((uint32_t)s << 16) | (uint32_t)cv1.us,
                       __ATOMIC_RELAXED, __HIP_MEMORY_SCOPE_SYSTEM);
    // hall: normal cached store (consumed by next dispatch)
    _Float16* hap = hall + (size_t)batch * (TT_ * HH_) + (size_t)t * HH_;
    hap[u0] = (_Float16)h0;
    hap[u1] = (_Float16)h1;
  }
}

// ---------------------------------------------------------------------------
// Kernel 3: out[b][t][o] = h_all[b][t][:] @ fc_W.T + fc_b   (fp32 out)
// ---------------------------------------------------------------------------
__global__ __launch_bounds__(256) void fc_gemm_k(
    const _Float16* __restrict__ hall, const float* __restrict__ fcW,
    const float* __restrict__ fcb, float* __restrict__ out)
{
  __shared__ _Float16 As[128][40];
  __shared__ _Float16 Bs[128][40];
  const int bn = blockIdx.x & 1;
  const int bm = blockIdx.x >> 1;
  const int M0 = bm * 128, N0 = bn * 128;
  const int tid = threadIdx.x;
  const int w = tid >> 6, l = tid & 63, lg = l >> 4, ln = l & 15;
  const int wm = w & 1, wn = w >> 1;
  const int sr = tid >> 1, sp = tid & 1;

  f32x4 acc[4][4];
  #pragma unroll
  for (int i = 0; i < 4; i++) {
    #pragma unroll
    for (int j = 0; j < 4; j++) acc[i][j] = (f32x4){0.f, 0.f, 0.f, 0.f};
  }

  for (int K0 = 0; K0 < HH_; K0 += 32) {
    __syncthreads();
    {
      const _Float16* s0 = hall + (size_t)(M0 + sr) * HH_ + K0 + sp * 16;
      *(uint4*)&As[sr][sp * 16]     = ((const uint4*)s0)[0];
      *(uint4*)&As[sr][sp * 16 + 8] = ((const uint4*)s0)[1];
      const float* s1 = fcW + (size_t)(N0 + sr) * HH_ + K0 + sp * 16;
      float4 g0 = ((const float4*)s1)[0], g1 = ((const float4*)s1)[1];
      float4 g2 = ((const float4*)s1)[2], g3 = ((const float4*)s1)[3];
      *(half8*)&Bs[sr][sp * 16]     = cvt8(g0, g1);
      *(half8*)&Bs[sr][sp * 16 + 8] = cvt8(g2, g3);
    }
    __syncthreads();
    half8 af[4], bf[4];
    #pragma unroll
    for (int i = 0; i < 4; i++) af[i] = *(const half8*)&As[wm * 64 + i * 16 + ln][lg * 8];
    #pragma unroll
    for (int j = 0; j < 4; j++) bf[j] = *(const half8*)&Bs[wn * 64 + j * 16 + ln][lg * 8];
    #pragma unroll
    for (int i = 0; i < 4; i++) {
      #pragma unroll
      for (int j = 0; j < 4; j++)
        acc[i][j] = __builtin_amdgcn_mfma_f32_16x16x32_f16(af[i], bf[j], acc[i][j], 0, 0, 0);
    }
  }

  #pragma unroll
  for (int j = 0; j < 4; j++) {
    const int ncol = N0 + wn * 64 + j * 16 + ln;
    const float bias = fcb[ncol];
    #pragma unroll
    for (int i = 0; i < 4; i++) {
      #pragma unroll
      for (int rr = 0; rr < 4; rr++) {
        const int m = M0 + wm * 64 + i * 16 + lg * 4 + rr;
        out[(size_t)m * OO_ + ncol] = acc[i][j][rr] + bias;
      }
    }
  }
}

extern "C" void kernel_launch(void* const* d_in, const int* in_sizes, int n_in,
                              void* d_out, int out_size, void* d_ws, size_t ws_size,
                              hipStream_t stream) {
  (void)in_sizes; (void)n_in; (void)out_size;
  if (ws_size < WS_NEEDED) return;  // diagnostic: output stays zero -> absmax ~0.39

  const float* x   = (const float*)d_in[0];
  const float* Wih = (const float*)d_in[1];
  const float* Whh = (const float*)d_in[2];
  const float* bih = (const float*)d_in[3];
  const float* bhh = (const float*)d_in[4];
  const float* fcW = (const float*)d_in[5];
  const float* fcb = (const float*)d_in[6];
  float* out = (float*)d_out;

  char* ws = (char*)d_ws;
  _Float16* gx   = (_Float16*)(ws + GX_OFF);
  _Float16* hall = (_Float16*)(ws + HALL_OFF);
  uint32_t* hx2  = (uint32_t*)(ws + HX2_OFF);

  // reset tagged h words: tag=0, h=0 == step-0 initial state (every call:
  // graph replays reuse ws)
  (void)hipMemsetAsync(ws + HX2_OFF, 0, HX2_BYTES, stream);

  gates_gemm_k<<<dim3(4096), dim3(256), 0, stream>>>(x, Wih, bih, bhh, gx);
  lstm_rec_k<<<dim3(64), dim3(256), 0, stream>>>(Whh, gx, hall, hx2);
  fc_gemm_k<<<dim3(512), dim3(256), 0, stream>>>(hall, fcW, fcb, out);
}

// Round 6
// 4251.218 us; speedup vs baseline: 1.2541x; 1.1945x over previous
//
#include <hip/hip_runtime.h>
#include <stdint.h>

typedef _Float16 half8 __attribute__((ext_vector_type(8)));
typedef float f32x4 __attribute__((ext_vector_type(4)));

static constexpr int BN_ = 64;    // batch
static constexpr int TT_ = 512;   // time steps
static constexpr int II_ = 256;   // input dim
static constexpr int HH_ = 512;   // hidden dim
static constexpr int GG_ = 2048;  // 4*H
static constexpr int OO_ = 256;   // output dim

// workspace layout (bytes)
static constexpr size_t GX_OFF    = 0;
static constexpr size_t GX_BYTES  = (size_t)TT_ * BN_ * GG_ * 2;        // 128 MiB fp16 [t][b][g']
static constexpr size_t HT_OFF    = GX_OFF + GX_BYTES;
static constexpr size_t HT_BYTES  = (size_t)(TT_ + 1) * BN_ * HH_ * 2;  // 32.06 MiB fp16 [slot][b][u]
static constexpr size_t FLAG_OFF  = HT_OFF + HT_BYTES;
static constexpr size_t FLAG_BYTES= (size_t)(TT_ + 1) * 4 * 64 * 4;     // [slot][bg][wave] flags
static constexpr size_t WS_NEEDED = FLAG_OFF + FLAG_BYTES;

__device__ __forceinline__ float sigm(float x)  { return 1.0f / (1.0f + __expf(-x)); }
__device__ __forceinline__ float tanha(float x) { return 1.0f - 2.0f / (__expf(2.0f * x) + 1.0f); }

__device__ __forceinline__ half8 cvt8(float4 a, float4 b) {
  half8 r;
  r[0]=(_Float16)a.x; r[1]=(_Float16)a.y; r[2]=(_Float16)a.z; r[3]=(_Float16)a.w;
  r[4]=(_Float16)b.x; r[5]=(_Float16)b.y; r[6]=(_Float16)b.z; r[7]=(_Float16)b.w;
  return r;
}

// ---------------------------------------------------------------------------
// Kernel 1: gates_x[t][b][g'] = (x @ W_ih.T)[b,t,R(g')] + b_ih[R] + b_hh[R]
// g' = 4*u + gate; R(g') = (g'&3)*512 + (g'>>2)
// ---------------------------------------------------------------------------
__global__ __launch_bounds__(256) void gates_gemm_k(
    const float* __restrict__ x, const float* __restrict__ Wih,
    const float* __restrict__ bih, const float* __restrict__ bhh,
    _Float16* __restrict__ gx)
{
  __shared__ _Float16 As[128][40];
  __shared__ _Float16 Bs[128][40];
  const int bn = blockIdx.x & 15;
  const int bm = blockIdx.x >> 4;
  const int M0 = bm * 128, N0 = bn * 128;
  const int tid = threadIdx.x;
  const int w = tid >> 6, l = tid & 63, lg = l >> 4, ln = l & 15;
  const int wm = w & 1, wn = w >> 1;
  const int sr = tid >> 1, sp = tid & 1;
  const int nglob = N0 + sr;
  const int Rrow = (nglob & 3) * HH_ + (nglob >> 2);

  f32x4 acc[4][4];
  #pragma unroll
  for (int i = 0; i < 4; i++) {
    #pragma unroll
    for (int j = 0; j < 4; j++) acc[i][j] = (f32x4){0.f, 0.f, 0.f, 0.f};
  }

  for (int K0 = 0; K0 < II_; K0 += 32) {
    __syncthreads();
    {
      const float* s0 = x + (size_t)(M0 + sr) * II_ + K0 + sp * 16;
      float4 f0 = ((const float4*)s0)[0], f1 = ((const float4*)s0)[1];
      float4 f2 = ((const float4*)s0)[2], f3 = ((const float4*)s0)[3];
      *(half8*)&As[sr][sp * 16]     = cvt8(f0, f1);
      *(half8*)&As[sr][sp * 16 + 8] = cvt8(f2, f3);
      const float* s1 = Wih + (size_t)Rrow * II_ + K0 + sp * 16;
      float4 g0 = ((const float4*)s1)[0], g1 = ((const float4*)s1)[1];
      float4 g2 = ((const float4*)s1)[2], g3 = ((const float4*)s1)[3];
      *(half8*)&Bs[sr][sp * 16]     = cvt8(g0, g1);
      *(half8*)&Bs[sr][sp * 16 + 8] = cvt8(g2, g3);
    }
    __syncthreads();
    half8 af[4], bf[4];
    #pragma unroll
    for (int i = 0; i < 4; i++) af[i] = *(const half8*)&As[wm * 64 + i * 16 + ln][lg * 8];
    #pragma unroll
    for (int j = 0; j < 4; j++) bf[j] = *(const half8*)&Bs[wn * 64 + j * 16 + ln][lg * 8];
    #pragma unroll
    for (int i = 0; i < 4; i++) {
      #pragma unroll
      for (int j = 0; j < 4; j++)
        acc[i][j] = __builtin_amdgcn_mfma_f32_16x16x32_f16(af[i], bf[j], acc[i][j], 0, 0, 0);
    }
  }

  #pragma unroll
  for (int j = 0; j < 4; j++) {
    const int ncol = N0 + wn * 64 + j * 16 + ln;
    const int R = (ncol & 3) * HH_ + (ncol >> 2);
    const float bias = bih[R] + bhh[R];
    #pragma unroll
    for (int i = 0; i < 4; i++) {
      #pragma unroll
      for (int rr = 0; rr < 4; rr++) {
        const int m = M0 + wm * 64 + i * 16 + lg * 4 + rr;
        const int bb = m >> 9, tt = m & 511;
        gx[(size_t)tt * (BN_ * GG_) + (size_t)bb * GG_ + ncol] =
            (_Float16)(acc[i][j][rr] + bias);
      }
    }
  }
}

// ---------------------------------------------------------------------------
// Kernel 2: persistent LSTM recurrence — unique-slot exchange, single store,
// per-wave flags, no barriers.
// 64 blocks = 4 batch-groups (mg) x 16 unit-slices (nb). W_hh in VGPRs.
// ht[slot][b][u]: slot s = h_s (slot 0 = zeros = h_0); doubles as FC input.
// Per step: poll 64 wave-flags of own bg (1/lane) -> bulk 256B/lane system
// loads -> 32 MFMA -> cell -> 2 fp16 system stores -> vmcnt(0) -> wave flag.
// Unique slots: no WAW, no parity discipline. Waves fully independent.
// ---------------------------------------------------------------------------
__global__ __launch_bounds__(256, 1) void lstm_rec_k(
    const float* __restrict__ Whh, const _Float16* __restrict__ gx,
    _Float16* __restrict__ ht, uint32_t* __restrict__ flags)
{
  const int bid = blockIdx.x;
  const int mg = bid >> 4, nb = bid & 15;
  const int tid = threadIdx.x;
  const int w = tid >> 6, l = tid & 63, lg = l >> 4, ln = l & 15;
  const int batch = mg * 16 + ln;

  // Preload W_hh fragments: A[row=gate-row g'][k=unit], rows permuted g'=4u+gate.
  half8 a0[16], a1[16];
  #pragma unroll
  for (int s2 = 0; s2 < 2; s2++) {
    const int gp = nb * 128 + 32 * w + s2 * 16 + ln;
    const int Rr = (gp & 3) * HH_ + (gp >> 2);
    const float* wp = Whh + (size_t)Rr * HH_;
    #pragma unroll
    for (int ks = 0; ks < 16; ks++) {
      const float* p = wp + ks * 32 + lg * 8;
      float4 f0 = ((const float4*)p)[0];
      float4 f1 = ((const float4*)p)[1];
      if (s2 == 0) a0[ks] = cvt8(f0, f1); else a1[ks] = cvt8(f0, f1);
    }
  }

  const int u0 = nb * 32 + 8 * w + lg;       // hidden unit of acc0's lane
  const int u1 = u0 + 4;                     // hidden unit of acc1's lane
  const int g0 = nb * 128 + 32 * w + lg * 4; // first gate-row (i-gate) of u0
  const int wid = nb * 4 + w;                // wave id within batch-group

  float c0 = 0.f, c1 = 0.f;

  for (int s = 1; s <= TT_; ++s) {
    const int t = s - 1;
    // gx prefetch (normal cached loads; in flight while we poll)
    const _Float16* gxp = gx + (size_t)t * (BN_ * GG_) + (size_t)batch * GG_ + g0;
    uint2 ga = *(const uint2*)gxp;
    uint2 gb = *(const uint2*)(gxp + 16);

    // poll the 64 producer-wave flags of our batch-group for slot t
    // (slot 0 is memset -> skip poll at t==0)
    if (t > 0) {
      const uint32_t* fp_ = flags + ((size_t)t * 4 + mg) * 64 + l;
      uint32_t v; int guard = 0;
      do {
        v = __hip_atomic_load(fp_, __ATOMIC_RELAXED, __HIP_MEMORY_SCOPE_SYSTEM);
        if (++guard > (1 << 20)) break;   // safety valve
      } while (!__all(v != 0));
    }

    // bulk: lane reads its batch row of slot t; B-frag k-units 32ks+8lg+[0..8)
    const unsigned long long* hin = (const unsigned long long*)(
        ht + (size_t)t * (BN_ * HH_) + (size_t)batch * HH_);
    unsigned long long hw[32];
    #pragma unroll
    for (int ks = 0; ks < 16; ks++) {
      const int e = 8 * ks + 2 * lg;
      hw[2 * ks]     = __hip_atomic_load(hin + e,     __ATOMIC_RELAXED, __HIP_MEMORY_SCOPE_SYSTEM);
      hw[2 * ks + 1] = __hip_atomic_load(hin + e + 1, __ATOMIC_RELAXED, __HIP_MEMORY_SCOPE_SYSTEM);
    }

    f32x4 acc0 = {0.f, 0.f, 0.f, 0.f}, acc1 = {0.f, 0.f, 0.f, 0.f};
    #pragma unroll
    for (int ks = 0; ks < 16; ks++) {
      union { unsigned long long q[2]; half8 h; } uq;
      uq.q[0] = hw[2 * ks]; uq.q[1] = hw[2 * ks + 1];
      acc0 = __builtin_amdgcn_mfma_f32_16x16x32_f16(a0[ks], uq.h, acc0, 0, 0, 0);
      acc1 = __builtin_amdgcn_mfma_f32_16x16x32_f16(a1[ks], uq.h, acc1, 0, 0, 0);
    }

    // lane-local cell update: acc regs = i,f,g,o recurrent preacts
    union { uint2 u; _Float16 h[4]; } ua, ub;
    ua.u = ga; ub.u = gb;
    float iv = sigm(acc0[0] + (float)ua.h[0]);
    float fv = sigm(acc0[1] + (float)ua.h[1]);
    float gv = tanha(acc0[2] + (float)ua.h[2]);
    float ov = sigm(acc0[3] + (float)ua.h[3]);
    c0 = fv * c0 + iv * gv;
    const float h0 = ov * tanha(c0);

    iv = sigm(acc1[0] + (float)ub.h[0]);
    fv = sigm(acc1[1] + (float)ub.h[1]);
    gv = tanha(acc1[2] + (float)ub.h[2]);
    ov = sigm(acc1[3] + (float)ub.h[3]);
    c1 = fv * c1 + iv * gv;
    const float h1 = ov * tanha(c1);

    // single store of h into slot s (write-through to coherence point)
    unsigned short* hp = (unsigned short*)(ht + (size_t)s * (BN_ * HH_) + (size_t)batch * HH_);
    union { _Float16 f; unsigned short us; } cv0, cv1;
    cv0.f = (_Float16)h0; cv1.f = (_Float16)h1;
    __hip_atomic_store(&hp[u0], cv0.us, __ATOMIC_RELAXED, __HIP_MEMORY_SCOPE_SYSTEM);
    __hip_atomic_store(&hp[u1], cv1.us, __ATOMIC_RELAXED, __HIP_MEMORY_SCOPE_SYSTEM);

    asm volatile("s_waitcnt vmcnt(0)" ::: "memory");  // h stores at coherence point
    if (l == 0) {
      uint32_t* fs = flags + ((size_t)s * 4 + mg) * 64 + wid;
      __hip_atomic_store(fs, 1u, __ATOMIC_RELAXED, __HIP_MEMORY_SCOPE_SYSTEM);
    }
  }
}

// ---------------------------------------------------------------------------
// Kernel 3: out[b][t][o] = ht[t+1][b][:] @ fc_W.T + fc_b   (fp32 out)
// M=32768 (m=b*512+t), N=256, K=512.
// ---------------------------------------------------------------------------
__global__ __launch_bounds__(256) void fc_gemm_k(
    const _Float16* __restrict__ ht, const float* __restrict__ fcW,
    const float* __restrict__ fcb, float* __restrict__ out)
{
  __shared__ _Float16 As[128][40];
  __shared__ _Float16 Bs[128][40];
  const int bn = blockIdx.x & 1;
  const int bm = blockIdx.x >> 1;
  const int M0 = bm * 128, N0 = bn * 128;
  const int tid = threadIdx.x;
  const int w = tid >> 6, l = tid & 63, lg = l >> 4, ln = l & 15;
  const int wm = w & 1, wn = w >> 1;
  const int sr = tid >> 1, sp = tid & 1;

  f32x4 acc[4][4];
  #pragma unroll
  for (int i = 0; i < 4; i++) {
    #pragma unroll
    for (int j = 0; j < 4; j++) acc[i][j] = (f32x4){0.f, 0.f, 0.f, 0.f};
  }

  const int m_ = M0 + sr;
  const int bb = m_ >> 9, tt = m_ & 511;
  const _Float16* arow = ht + (size_t)(tt + 1) * (BN_ * HH_) + (size_t)bb * HH_;

  for (int K0 = 0; K0 < HH_; K0 += 32) {
    __syncthreads();
    {
      const _Float16* s0 = arow + K0 + sp * 16;
      *(uint4*)&As[sr][sp * 16]     = ((const uint4*)s0)[0];
      *(uint4*)&As[sr][sp * 16 + 8] = ((const uint4*)s0)[1];
      const float* s1 = fcW + (size_t)(N0 + sr) * HH_ + K0 + sp * 16;
      float4 g0 = ((const float4*)s1)[0], g1 = ((const float4*)s1)[1];
      float4 g2 = ((const float4*)s1)[2], g3 = ((const float4*)s1)[3];
      *(half8*)&Bs[sr][sp * 16]     = cvt8(g0, g1);
      *(half8*)&Bs[sr][sp * 16 + 8] = cvt8(g2, g3);
    }
    __syncthreads();
    half8 af[4], bf[4];
    #pragma unroll
    for (int i = 0; i < 4; i++) af[i] = *(const half8*)&As[wm * 64 + i * 16 + ln][lg * 8];
    #pragma unroll
    for (int j = 0; j < 4; j++) bf[j] = *(const half8*)&Bs[wn * 64 + j * 16 + ln][lg * 8];
    #pragma unroll
    for (int i = 0; i < 4; i++) {
      #pragma unroll
      for (int j = 0; j < 4; j++)
        acc[i][j] = __builtin_amdgcn_mfma_f32_16x16x32_f16(af[i], bf[j], acc[i][j], 0, 0, 0);
    }
  }

  #pragma unroll
  for (int j = 0; j < 4; j++) {
    const int ncol = N0 + wn * 64 + j * 16 + ln;
    const float bias = fcb[ncol];
    #pragma unroll
    for (int i = 0; i < 4; i++) {
      #pragma unroll
      for (int rr = 0; rr < 4; rr++) {
        const int m = M0 + wm * 64 + i * 16 + lg * 4 + rr;
        out[(size_t)m * OO_ + ncol] = acc[i][j][rr] + bias;
      }
    }
  }
}

extern "C" void kernel_launch(void* const* d_in, const int* in_sizes, int n_in,
                              void* d_out, int out_size, void* d_ws, size_t ws_size,
                              hipStream_t stream) {
  (void)in_sizes; (void)n_in; (void)out_size;
  if (ws_size < WS_NEEDED) return;  // diagnostic: output stays zero -> absmax ~0.39

  const float* x   = (const float*)d_in[0];
  const float* Wih = (const float*)d_in[1];
  const float* Whh = (const float*)d_in[2];
  const float* bih = (const float*)d_in[3];
  const float* bhh = (const float*)d_in[4];
  const float* fcW = (const float*)d_in[5];
  const float* fcb = (const float*)d_in[6];
  float* out = (float*)d_out;

  char* ws = (char*)d_ws;
  _Float16* gx    = (_Float16*)(ws + GX_OFF);
  _Float16* ht    = (_Float16*)(ws + HT_OFF);
  uint32_t* flags = (uint32_t*)(ws + FLAG_OFF);

  // reset slot 0 (= h_0 = 0) and all flags every call (graph replays reuse ws)
  (void)hipMemsetAsync(ws + HT_OFF, 0, (size_t)BN_ * HH_ * 2, stream);
  (void)hipMemsetAsync(ws + FLAG_OFF, 0, FLAG_BYTES, stream);

  gates_gemm_k<<<dim3(4096), dim3(256), 0, stream>>>(x, Wih, bih, bhh, gx);
  lstm_rec_k<<<dim3(64), dim3(256), 0, stream>>>(Whh, gx, ht, flags);
  fc_gemm_k<<<dim3(512), dim3(256), 0, stream>>>(ht, fcW, fcb, out);
}

// Round 7
// 2056.792 us; speedup vs baseline: 2.5922x; 2.0669x over previous
//
#include <hip/hip_runtime.h>
#include <stdint.h>

typedef _Float16 half8 __attribute__((ext_vector_type(8)));
typedef float f32x4 __attribute__((ext_vector_type(4)));

static constexpr int BN_ = 64;    // batch
static constexpr int TT_ = 512;   // time steps
static constexpr int II_ = 256;   // input dim
static constexpr int HH_ = 512;   // hidden dim
static constexpr int GG_ = 2048;  // 4*H
static constexpr int OO_ = 256;   // output dim

// workspace layout (bytes)
static constexpr size_t GX_OFF    = 0;
static constexpr size_t GX_BYTES  = (size_t)TT_ * BN_ * GG_ * 2;   // 128 MiB fp16 [t][b][g']
static constexpr size_t HALL_OFF  = GX_OFF + GX_BYTES;
static constexpr size_t HALL_BYTES= (size_t)BN_ * TT_ * HH_ * 2;   // 32 MiB fp16 [b][t][u]
static constexpr size_t X_OFF     = HALL_OFF + HALL_BYTES;
static constexpr size_t X_BYTES   = (size_t)2 * 4 * 64 * 16 * 8 * 2; // 128 KiB [par][bg][wave][row16][8u]
static constexpr size_t FLAG_OFF  = X_OFF + X_BYTES;
static constexpr size_t FLAG_BYTES= (size_t)64 * 128;              // one 128B slot per block
static constexpr size_t WS_NEEDED = FLAG_OFF + FLAG_BYTES;

__device__ __forceinline__ float sigm(float x)  { return 1.0f / (1.0f + __expf(-x)); }
__device__ __forceinline__ float tanha(float x) { return 1.0f - 2.0f / (__expf(2.0f * x) + 1.0f); }

__device__ __forceinline__ half8 cvt8(float4 a, float4 b) {
  half8 r;
  r[0]=(_Float16)a.x; r[1]=(_Float16)a.y; r[2]=(_Float16)a.z; r[3]=(_Float16)a.w;
  r[4]=(_Float16)b.x; r[5]=(_Float16)b.y; r[6]=(_Float16)b.z; r[7]=(_Float16)b.w;
  return r;
}

// Permutation (unit-interleaved so each lane owns ADJACENT units):
// g' = nb*128 + w*32 + s2*16 + r  ->  unit u = nb*32 + w*8 + (r>>2)*2 + s2,
// gate = r&3.  Original row R(g') = gate*512 + u.

// ---------------------------------------------------------------------------
// Kernel 1: gates_x[t][b][g'] = (x @ W_ih.T)[b,t,R(g')] + b_ih[R] + b_hh[R]
// M=32768 (m=b*512+t), N=2048, K=256. 128x128 tile, BK=32, 4 waves.
// ---------------------------------------------------------------------------
__global__ __launch_bounds__(256) void gates_gemm_k(
    const float* __restrict__ x, const float* __restrict__ Wih,
    const float* __restrict__ bih, const float* __restrict__ bhh,
    _Float16* __restrict__ gx)
{
  __shared__ _Float16 As[128][40];
  __shared__ _Float16 Bs[128][40];
  const int bn = blockIdx.x & 15;
  const int bm = blockIdx.x >> 4;
  const int M0 = bm * 128, N0 = bn * 128;
  const int tid = threadIdx.x;
  const int w = tid >> 6, l = tid & 63, lg = l >> 4, ln = l & 15;
  const int wm = w & 1, wn = w >> 1;
  const int sr = tid >> 1, sp = tid & 1;
  // staging row sr of the B tile corresponds to permuted column N0+sr
  const int nglob = N0 + sr;
  {
  }
  const int qg = nglob & 127;
  const int Rrow = (qg & 3) * HH_ +
                   ((nglob >> 7) << 5) + ((qg >> 5) << 3) +
                   (((qg & 15) >> 2) << 1) + ((qg >> 4) & 1);

  f32x4 acc[4][4];
  #pragma unroll
  for (int i = 0; i < 4; i++) {
    #pragma unroll
    for (int j = 0; j < 4; j++) acc[i][j] = (f32x4){0.f, 0.f, 0.f, 0.f};
  }

  for (int K0 = 0; K0 < II_; K0 += 32) {
    __syncthreads();
    {
      const float* s0 = x + (size_t)(M0 + sr) * II_ + K0 + sp * 16;
      float4 f0 = ((const float4*)s0)[0], f1 = ((const float4*)s0)[1];
      float4 f2 = ((const float4*)s0)[2], f3 = ((const float4*)s0)[3];
      *(half8*)&As[sr][sp * 16]     = cvt8(f0, f1);
      *(half8*)&As[sr][sp * 16 + 8] = cvt8(f2, f3);
      const float* s1 = Wih + (size_t)Rrow * II_ + K0 + sp * 16;
      float4 g0 = ((const float4*)s1)[0], g1 = ((const float4*)s1)[1];
      float4 g2 = ((const float4*)s1)[2], g3 = ((const float4*)s1)[3];
      *(half8*)&Bs[sr][sp * 16]     = cvt8(g0, g1);
      *(half8*)&Bs[sr][sp * 16 + 8] = cvt8(g2, g3);
    }
    __syncthreads();
    half8 af[4], bf[4];
    #pragma unroll
    for (int i = 0; i < 4; i++) af[i] = *(const half8*)&As[wm * 64 + i * 16 + ln][lg * 8];
    #pragma unroll
    for (int j = 0; j < 4; j++) bf[j] = *(const half8*)&Bs[wn * 64 + j * 16 + ln][lg * 8];
    #pragma unroll
    for (int i = 0; i < 4; i++) {
      #pragma unroll
      for (int j = 0; j < 4; j++)
        acc[i][j] = __builtin_amdgcn_mfma_f32_16x16x32_f16(af[i], bf[j], acc[i][j], 0, 0, 0);
    }
  }

  #pragma unroll
  for (int j = 0; j < 4; j++) {
    const int ncol = N0 + wn * 64 + j * 16 + ln;
    const int q = ncol & 127;
    const int u = ((ncol >> 7) << 5) + ((q >> 5) << 3) + (((q & 15) >> 2) << 1) + ((q >> 4) & 1);
    const int R = (q & 3) * HH_ + u;
    const float bias = bih[R] + bhh[R];
    #pragma unroll
    for (int i = 0; i < 4; i++) {
      #pragma unroll
      for (int rr = 0; rr < 4; rr++) {
        const int m = M0 + wm * 64 + i * 16 + lg * 4 + rr;
        const int bb = m >> 9, tt = m & 511;
        gx[(size_t)tt * (BN_ * GG_) + (size_t)bb * GG_ + ncol] =
            (_Float16)(acc[i][j][rr] + bias);
      }
    }
  }
}

// ---------------------------------------------------------------------------
// Kernel 2: persistent LSTM recurrence — r2 flag protocol + coalesced compact
// exchange. 64 blocks = 4 batch-groups (mg) x 16 unit-slices (nb).
// X[par][mg][wave64][row16][8units]: each producer wave's h output is ONE
// fully-coalesced 256B dword store (full lines -> no MALL RMW). Consumer
// MFMA slice ks at lane (lg,ln) reads tile ks*4+lg, row ln (units in order).
// ---------------------------------------------------------------------------
__global__ __launch_bounds__(256, 1) void lstm_rec_k(
    const float* __restrict__ Whh, const _Float16* __restrict__ gx,
    _Float16* __restrict__ hall, uint32_t* __restrict__ xb,
    int* __restrict__ flags)
{
  const int bid = blockIdx.x;
  const int mg = bid >> 4, nb = bid & 15;
  const int tid = threadIdx.x;
  const int w = tid >> 6, l = tid & 63, lg = l >> 4, ln = l & 15;
  const int batch = mg * 16 + ln;

  // Preload W_hh fragments, rows per interleaved permutation.
  // A-frag row ln of fragment s2: u = nb*32+8w+2*(ln>>2)+s2, gate=ln&3.
  half8 a0[16], a1[16];
  #pragma unroll
  for (int s2 = 0; s2 < 2; s2++) {
    const int u_ = nb * 32 + 8 * w + 2 * (ln >> 2) + s2;
    const int Rr = (ln & 3) * HH_ + u_;
    const float* wp = Whh + (size_t)Rr * HH_;
    #pragma unroll
    for (int ks = 0; ks < 16; ks++) {
      const float* p = wp + ks * 32 + lg * 8;
      float4 f0 = ((const float4*)p)[0];
      float4 f1 = ((const float4*)p)[1];
      if (s2 == 0) a0[ks] = cvt8(f0, f1); else a1[ks] = cvt8(f0, f1);
    }
  }

  const int u0 = nb * 32 + 8 * w + 2 * lg;   // even unit of acc0's lane
  // u1 = u0 + 1 (adjacent) -> one packed dword store
  const int g0 = nb * 128 + 32 * w + 4 * lg; // first gate-row (i) of u0
  const int wid = nb * 4 + w;                // wave id within batch-group

  float c0 = 0.f, c1 = 0.f;
  int* myflag = flags + bid * 32;
  int* watch = flags + (mg * 16 + (tid & 15)) * 32;
  const bool spinner = (tid < 16) && (tid != nb);

  for (int s = 1; s <= TT_; ++s) {
    const int t = s - 1;
    // gx prefetch (cached; in flight while we poll)
    const _Float16* gxp = gx + (size_t)t * (BN_ * GG_) + (size_t)batch * GG_ + g0;
    uint2 ga = *(const uint2*)gxp;          // gates i,f,g,o of u0
    uint2 gb = *(const uint2*)(gxp + 16);   // gates i,f,g,o of u1

    // wait until all partner blocks have published h_{s-1}
    if (spinner) {
      int guard = 0;
      while (__hip_atomic_load(watch, __ATOMIC_RELAXED, __HIP_MEMORY_SCOPE_SYSTEM) < s - 1) {
        if (++guard > (1 << 20)) break;  // deadlock safety valve
      }
    }
    __syncthreads();

    // bulk: for slice ks, lane (lg,ln) reads tile ks*4+lg, row ln (16B = 2xb64)
    const unsigned long long* hin = (const unsigned long long*)xb +
        ((size_t)((t & 1) * 4 + mg) * 64) * 32 + (size_t)ln * 2;
    unsigned long long hw[32];
    #pragma unroll
    for (int ks = 0; ks < 16; ks++) {
      const size_t e = (size_t)(ks * 4 + lg) * 32;
      hw[2 * ks]     = __hip_atomic_load(hin + e,     __ATOMIC_RELAXED, __HIP_MEMORY_SCOPE_SYSTEM);
      hw[2 * ks + 1] = __hip_atomic_load(hin + e + 1, __ATOMIC_RELAXED, __HIP_MEMORY_SCOPE_SYSTEM);
    }

    f32x4 acc0 = {0.f, 0.f, 0.f, 0.f}, acc1 = {0.f, 0.f, 0.f, 0.f};
    #pragma unroll
    for (int ks = 0; ks < 16; ks++) {
      union { unsigned long long q[2]; half8 h; } uq;
      uq.q[0] = hw[2 * ks]; uq.q[1] = hw[2 * ks + 1];
      acc0 = __builtin_amdgcn_mfma_f32_16x16x32_f16(a0[ks], uq.h, acc0, 0, 0, 0);
      acc1 = __builtin_amdgcn_mfma_f32_16x16x32_f16(a1[ks], uq.h, acc1, 0, 0, 0);
    }

    // lane-local cell update: acc regs = i,f,g,o recurrent preacts
    union { uint2 u; _Float16 h[4]; } ua, ub;
    ua.u = ga; ub.u = gb;
    float iv = sigm(acc0[0] + (float)ua.h[0]);
    float fv = sigm(acc0[1] + (float)ua.h[1]);
    float gv = tanha(acc0[2] + (float)ua.h[2]);
    float ov = sigm(acc0[3] + (float)ua.h[3]);
    c0 = fv * c0 + iv * gv;
    const float h0 = ov * tanha(c0);

    iv = sigm(acc1[0] + (float)ub.h[0]);
    fv = sigm(acc1[1] + (float)ub.h[1]);
    gv = tanha(acc1[2] + (float)ub.h[2]);
    ov = sigm(acc1[3] + (float)ub.h[3]);
    c1 = fv * c1 + iv * gv;
    const float h1 = ov * tanha(c1);

    // pack h(u0), h(u0+1) into one dword
    union { _Float16 f; uint16_t u; } cv0, cv1;
    cv0.f = (_Float16)h0; cv1.f = (_Float16)h1;
    const uint32_t packed = ((uint32_t)cv1.u << 16) | (uint32_t)cv0.u;

    // X store: one fully-coalesced dword per lane (wave = 256B, 2 full lines)
    uint32_t* xp = xb + ((size_t)((s & 1) * 4 + mg) * 64 + wid) * 64 + ln * 4 + lg;
    __hip_atomic_store(xp, packed, __ATOMIC_RELAXED, __HIP_MEMORY_SCOPE_SYSTEM);
    // hall: cached dword store (consumed by next dispatch)
    *(uint32_t*)(hall + (size_t)batch * (TT_ * HH_) + (size_t)t * HH_ + u0) = packed;

    asm volatile("s_waitcnt vmcnt(0)" ::: "memory");  // h stores performed
    __syncthreads();                                   // all waves of block done
    if (tid == 0)
      __hip_atomic_store(myflag, s, __ATOMIC_RELAXED, __HIP_MEMORY_SCOPE_SYSTEM);
  }
}

// ---------------------------------------------------------------------------
// Kernel 3: out[b][t][o] = h_all[b][t][:] @ fc_W.T + fc_b   (fp32 out)
// M=32768, N=256, K=512.
// ---------------------------------------------------------------------------
__global__ __launch_bounds__(256) void fc_gemm_k(
    const _Float16* __restrict__ hall, const float* __restrict__ fcW,
    const float* __restrict__ fcb, float* __restrict__ out)
{
  __shared__ _Float16 As[128][40];
  __shared__ _Float16 Bs[128][40];
  const int bn = blockIdx.x & 1;
  const int bm = blockIdx.x >> 1;
  const int M0 = bm * 128, N0 = bn * 128;
  const int tid = threadIdx.x;
  const int w = tid >> 6, l = tid & 63, lg = l >> 4, ln = l & 15;
  const int wm = w & 1, wn = w >> 1;
  const int sr = tid >> 1, sp = tid & 1;

  f32x4 acc[4][4];
  #pragma unroll
  for (int i = 0; i < 4; i++) {
    #pragma unroll
    for (int j = 0; j < 4; j++) acc[i][j] = (f32x4){0.f, 0.f, 0.f, 0.f};
  }

  for (int K0 = 0; K0 < HH_; K0 += 32) {
    __syncthreads();
    {
      const _Float16* s0 = hall + (size_t)(M0 + sr) * HH_ + K0 + sp * 16;
      *(uint4*)&As[sr][sp * 16]     = ((const uint4*)s0)[0];
      *(uint4*)&As[sr][sp * 16 + 8] = ((const uint4*)s0)[1];
      const float* s1 = fcW + (size_t)(N0 + sr) * HH_ + K0 + sp * 16;
      float4 g0 = ((const float4*)s1)[0], g1 = ((const float4*)s1)[1];
      float4 g2 = ((const float4*)s1)[2], g3 = ((const float4*)s1)[3];
      *(half8*)&Bs[sr][sp * 16]     = cvt8(g0, g1);
      *(half8*)&Bs[sr][sp * 16 + 8] = cvt8(g2, g3);
    }
    __syncthreads();
    half8 af[4], bf[4];
    #pragma unroll
    for (int i = 0; i < 4; i++) af[i] = *(const half8*)&As[wm * 64 + i * 16 + ln][lg * 8];
    #pragma unroll
    for (int j = 0; j < 4; j++) bf[j] = *(const half8*)&Bs[wn * 64 + j * 16 + ln][lg * 8];
    #pragma unroll
    for (int i = 0; i < 4; i++) {
      #pragma unroll
      for (int j = 0; j < 4; j++)
        acc[i][j] = __builtin_amdgcn_mfma_f32_16x16x32_f16(af[i], bf[j], acc[i][j], 0, 0, 0);
    }
  }

  #pragma unroll
  for (int j = 0; j < 4; j++) {
    const int ncol = N0 + wn * 64 + j * 16 + ln;
    const float bias = fcb[ncol];
    #pragma unroll
    for (int i = 0; i < 4; i++) {
      #pragma unroll
      for (int rr = 0; rr < 4; rr++) {
        const int m = M0 + wm * 64 + i * 16 + lg * 4 + rr;
        out[(size_t)m * OO_ + ncol] = acc[i][j][rr] + bias;
      }
    }
  }
}

extern "C" void kernel_launch(void* const* d_in, const int* in_sizes, int n_in,
                              void* d_out, int out_size, void* d_ws, size_t ws_size,
                              hipStream_t stream) {
  (void)in_sizes; (void)n_in; (void)out_size;
  if (ws_size < WS_NEEDED) return;  // diagnostic: output stays zero -> absmax ~0.39

  const float* x   = (const float*)d_in[0];
  const float* Wih = (const float*)d_in[1];
  const float* Whh = (const float*)d_in[2];
  const float* bih = (const float*)d_in[3];
  const float* bhh = (const float*)d_in[4];
  const float* fcW = (const float*)d_in[5];
  const float* fcb = (const float*)d_in[6];
  float* out = (float*)d_out;

  char* ws = (char*)d_ws;
  _Float16* gx   = (_Float16*)(ws + GX_OFF);
  _Float16* hall = (_Float16*)(ws + HALL_OFF);
  uint32_t* xb   = (uint32_t*)(ws + X_OFF);
  int* flags     = (int*)(ws + FLAG_OFF);

  // reset X (h0 = 0) and flags every call (graph replays reuse ws)
  (void)hipMemsetAsync(ws + X_OFF, 0, X_BYTES + FLAG_BYTES, stream);

  gates_gemm_k<<<dim3(4096), dim3(256), 0, stream>>>(x, Wih, bih, bhh, gx);
  lstm_rec_k<<<dim3(64), dim3(256), 0, stream>>>(Whh, gx, hall, xb, flags);
  fc_gemm_k<<<dim3(512), dim3(256), 0, stream>>>(hall, fcW, fcb, out);
}